// Round 9
// baseline (700.152 us; speedup 1.0000x reference)
//
#include <hip/hip_runtime.h>
#include <hip/hip_bf16.h>

// GCN 3-layer: GCNConv -> BN -> ReLU (x2) -> GCNConv -> +residual
// N=50000, E=800000, D=128, fp32.
//
// Round 9 (= round 7 source, resubmitted through repeated infra timeouts):
// round-4 design with the broken mm LDS swizzle REVERTED (it read wrong W
// columns: f(c0)+4 != f(c0+4); also misaligned b128 LDS stores).
// The XCD-slicing experiment is unchanged:
//   - h stored SLICE-MAJOR: h8[8][N][16ch]; agg blocks pick slice = blockIdx&7
//     so each XCD owns one 3.2MB slice (fits its private 4MB L2).
//   - dinv folded into mm epilogue (h' = dinv*xW); agg needs only src index
//     per edge: out = dinv[dst]*(h'[dst] + sum h'[src]). No per-edge coef.
//   - agg wave = 1 node: 64 lanes = 16 channels x 4 edge slots, shfl reduce.

#define GCN_N 50000
#define GCN_E 800000
#define GCN_D 128
#define SLW 16   // slice width (channels); 8 slices of 64B

// ---------------------------------------------------------------- zero int buf
__global__ __launch_bounds__(256) void zero_kernel(int* __restrict__ p, int n) {
    int i = blockIdx.x * blockDim.x + threadIdx.x;
    if (i < n) p[i] = 0;
}

// ---------------------------------------------------------------- histogram
__global__ __launch_bounds__(256) void hist_kernel(const int* __restrict__ dst,
                                                   int* __restrict__ cnt, int nE) {
    int e = blockIdx.x * blockDim.x + threadIdx.x;
    if (e < nE) atomicAdd(&cnt[dst[e]], 1);
}

// ------------------------------------------------- multi-block prefix sum
__global__ __launch_bounds__(256) void block_reduce(const int* __restrict__ cnt,
                                                    int* __restrict__ bsum, int n) {
    int tid = threadIdx.x, lane = tid & 63, wid = tid >> 6;
    int i0 = blockIdx.x * 1024 + tid * 4;
    int s = 0;
    #pragma unroll
    for (int q = 0; q < 4; ++q)
        if (i0 + q < n) s += cnt[i0 + q];
    #pragma unroll
    for (int off = 32; off >= 1; off >>= 1) s += __shfl_xor(s, off);
    __shared__ int ws[4];
    if (lane == 0) ws[wid] = s;
    __syncthreads();
    if (tid == 0) bsum[blockIdx.x] = ws[0] + ws[1] + ws[2] + ws[3];
}

__global__ void scan_bsums(const int* __restrict__ bsum, int* __restrict__ boff,
                           int nb, int* __restrict__ row_last) {
    int lane = threadIdx.x;  // 64 threads
    int v = (lane < nb) ? bsum[lane] : 0;
    int sc = v;
    #pragma unroll
    for (int off = 1; off < 64; off <<= 1) {
        int t = __shfl_up(sc, off);
        if (lane >= off) sc += t;
    }
    if (lane < nb) boff[lane] = sc - v;
    if (lane == 63) *row_last = sc;  // row_ptr[N] = E
}

// row_ptr (exclusive scan), dinv = rsqrt(deg+1), zero cnt for fill cursor.
__global__ __launch_bounds__(256) void scan_apply(const int* __restrict__ cnt_in,
                                                  const int* __restrict__ boff,
                                                  int* __restrict__ row_ptr,
                                                  float* __restrict__ dinv,
                                                  int* __restrict__ cnt_zero, int n) {
    __shared__ int wsum[4];
    int tid = threadIdx.x, lane = tid & 63, wid = tid >> 6;
    int i0 = blockIdx.x * 1024 + tid * 4;
    int a0 = 0, a1 = 0, a2 = 0, a3 = 0;
    if (i0 + 0 < n) a0 = cnt_in[i0 + 0];
    if (i0 + 1 < n) a1 = cnt_in[i0 + 1];
    if (i0 + 2 < n) a2 = cnt_in[i0 + 2];
    if (i0 + 3 < n) a3 = cnt_in[i0 + 3];
    int tsum = a0 + a1 + a2 + a3;
    int sc = tsum;
    #pragma unroll
    for (int off = 1; off < 64; off <<= 1) {
        int t = __shfl_up(sc, off);
        if (lane >= off) sc += t;
    }
    if (lane == 63) wsum[wid] = sc;
    __syncthreads();
    int woff = 0;
    #pragma unroll
    for (int w = 0; w < 4; ++w)
        if (w < wid) woff += wsum[w];
    int excl = boff[blockIdx.x] + woff + (sc - tsum);
    if (i0 + 0 < n) { row_ptr[i0 + 0] = excl;                dinv[i0 + 0] = rsqrtf((float)a0 + 1.f); cnt_zero[i0 + 0] = 0; }
    if (i0 + 1 < n) { row_ptr[i0 + 1] = excl + a0;           dinv[i0 + 1] = rsqrtf((float)a1 + 1.f); cnt_zero[i0 + 1] = 0; }
    if (i0 + 2 < n) { row_ptr[i0 + 2] = excl + a0 + a1;      dinv[i0 + 2] = rsqrtf((float)a2 + 1.f); cnt_zero[i0 + 2] = 0; }
    if (i0 + 3 < n) { row_ptr[i0 + 3] = excl + a0 + a1 + a2; dinv[i0 + 3] = rsqrtf((float)a3 + 1.f); cnt_zero[i0 + 3] = 0; }
}

// ---------------------------------------------------------------- CSR fill
__global__ __launch_bounds__(256) void fill_kernel(const int* __restrict__ src,
                                                   const int* __restrict__ dst,
                                                   const int* __restrict__ row_ptr,
                                                   int* __restrict__ cur,
                                                   int* __restrict__ esrc, int nE) {
    int e = blockIdx.x * blockDim.x + threadIdx.x;
    if (e >= nE) return;
    int d = dst[e];
    int pos = row_ptr[d] + atomicAdd(&cur[d], 1);
    esrc[pos] = src[e];
}

// ------------------------------------------------- fold BN into scale/shift
__global__ void prep_kernel(const float* __restrict__ b, const float* __restrict__ g,
                            const float* __restrict__ be, const float* __restrict__ m,
                            const float* __restrict__ v, float* __restrict__ scale,
                            float* __restrict__ shift) {
    int c = threadIdx.x;
    float s = g[c] * rsqrtf(v[c] + 1e-5f);
    scale[c] = s;
    shift[c] = (b[c] - m[c]) * s + be[c];
}

// ---------------------------------------------------------------- matmul
// h8[slice][node][16] = dinv[node] * (A[node,:] @ W)[slice*16..+16)
// Block: 256 threads (16x16), tile 64 rows x 128 cols, BK=64, per-thread 4x8.
// (LDS layout identical to the round-3 version that passed correctness.)
__global__ __launch_bounds__(256) void mm_kernel(const float* __restrict__ A,
                                                 const float* __restrict__ W,
                                                 const float* __restrict__ dinv,
                                                 float* __restrict__ h8, int n) {
    __shared__ float As[64][68];
    __shared__ float Bs[64][132];
    int tid = threadIdx.x;
    int tx = tid & 15;
    int ty = tid >> 4;
    int row0 = blockIdx.x * 64;
    float acc[4][8] = {};

    for (int k0 = 0; k0 < 128; k0 += 64) {
        int ac = (tid & 15) * 4;
        int ar = tid >> 4;
        #pragma unroll
        for (int rr = 0; rr < 4; ++rr) {
            int r = ar + rr * 16;
            int gr = row0 + r;
            float4 v = make_float4(0.f, 0.f, 0.f, 0.f);
            if (gr < n) v = *(const float4*)&A[(size_t)gr * GCN_D + k0 + ac];
            *(float4*)&As[r][ac] = v;
        }
        int bc = (tid & 31) * 4;
        int br = tid >> 5;
        #pragma unroll
        for (int rr = 0; rr < 8; ++rr) {
            int r = br + rr * 8;
            float4 v = *(const float4*)&W[(size_t)(k0 + r) * GCN_D + bc];
            *(float4*)&Bs[r][bc] = v;
        }
        __syncthreads();
        #pragma unroll
        for (int kk = 0; kk < 64; ++kk) {
            float a[4];
            #pragma unroll
            for (int m = 0; m < 4; ++m) a[m] = As[ty * 4 + m][kk];
            float4 b0 = *(const float4*)&Bs[kk][tx * 8];
            float4 b1 = *(const float4*)&Bs[kk][tx * 8 + 4];
            float b[8] = {b0.x, b0.y, b0.z, b0.w, b1.x, b1.y, b1.z, b1.w};
            #pragma unroll
            for (int m = 0; m < 4; ++m)
                #pragma unroll
                for (int q = 0; q < 8; ++q) acc[m][q] += a[m] * b[q];
        }
        __syncthreads();
    }
    // epilogue: scale by dinv, write slice-major
    int slice = tx >> 1;             // channels tx*8..+7 lie in slice tx>>1
    int off = (tx & 1) * 8;
    #pragma unroll
    for (int m = 0; m < 4; ++m) {
        int gr = row0 + ty * 4 + m;
        if (gr < n) {
            float dv = dinv[gr];
            float* p = h8 + ((size_t)slice * n + gr) * SLW + off;
            *(float4*)&p[0] = make_float4(acc[m][0] * dv, acc[m][1] * dv,
                                          acc[m][2] * dv, acc[m][3] * dv);
            *(float4*)&p[4] = make_float4(acc[m][4] * dv, acc[m][5] * dv,
                                          acc[m][6] * dv, acc[m][7] * dv);
        }
    }
}

// ------------------------------------------------- fused aggregate + epilogue
// Grid: (slices=8) x node-blocks; slice = blockIdx&7 -> pinned to one XCD by
// round-robin block->XCD mapping; per-XCD slice footprint 3.2MB fits 4MB L2.
// Wave = 1 node: lane = (c=lane&15, e4=lane>>4) -> 16 channels x 4 edge slots.
// FINAL=0: out = relu(acc*dinv*scale + shift); FINAL=1: out = acc*dinv + b3 + xres.
template <int FINAL>
__global__ __launch_bounds__(256) void agg_kernel(const float* __restrict__ h8,
                                                  const int* __restrict__ row_ptr,
                                                  const int* __restrict__ esrc,
                                                  const float* __restrict__ dinv,
                                                  const float* __restrict__ scale,
                                                  const float* __restrict__ shift,
                                                  const float* __restrict__ xres,
                                                  float* __restrict__ out, int n) {
    int slice = blockIdx.x & 7;
    int bnode = blockIdx.x >> 3;
    int wid = threadIdx.x >> 6, lane = threadIdx.x & 63;
    int node = bnode * 4 + wid;
    if (node >= n) return;
    int c = lane & 15, e4 = lane >> 4;
    const float* __restrict__ hs = h8 + (size_t)slice * n * SLW;
    int start = row_ptr[node], end = row_ptr[node + 1];
    float acc = (e4 == 0) ? hs[(size_t)node * SLW + c] : 0.f;  // self term
    int j = start;
    for (; j + 8 <= end; j += 8) {
        float v0 = hs[(size_t)esrc[j + e4] * SLW + c];
        float v1 = hs[(size_t)esrc[j + 4 + e4] * SLW + c];
        acc += v0;
        acc += v1;
    }
    int j0 = j + e4, j1 = j + 4 + e4;
    if (j0 < end) acc += hs[(size_t)esrc[j0] * SLW + c];
    if (j1 < end) acc += hs[(size_t)esrc[j1] * SLW + c];
    // reduce across the 4 edge-slot groups
    acc += __shfl_xor(acc, 16);
    acc += __shfl_xor(acc, 32);
    if (lane < 16) {
        int ch = slice * SLW + c;
        float v = acc * dinv[node];
        float o;
        if (FINAL) {
            o = v + scale[ch] + xres[(size_t)node * GCN_D + ch];  // scale = b3
        } else {
            o = fmaxf(v * scale[ch] + shift[ch], 0.f);
        }
        out[(size_t)node * GCN_D + ch] = o;
    }
}

// ---------------------------------------------------------------- launch
extern "C" void kernel_launch(void* const* d_in, const int* in_sizes, int n_in,
                              void* d_out, int out_size, void* d_ws, size_t ws_size,
                              hipStream_t stream) {
    (void)in_sizes; (void)n_in; (void)out_size; (void)ws_size;
    const int N = GCN_N, E = GCN_E, D = GCN_D;

    const float* x   = (const float*)d_in[0];
    const float* W1  = (const float*)d_in[1];
    const float* b1  = (const float*)d_in[2];
    const float* g1  = (const float*)d_in[3];
    const float* be1 = (const float*)d_in[4];
    const float* m1  = (const float*)d_in[5];
    const float* v1  = (const float*)d_in[6];
    const float* W2  = (const float*)d_in[7];
    const float* b2  = (const float*)d_in[8];
    const float* g2  = (const float*)d_in[9];
    const float* be2 = (const float*)d_in[10];
    const float* m2  = (const float*)d_in[11];
    const float* v2  = (const float*)d_in[12];
    const float* W3  = (const float*)d_in[13];
    const float* b3  = (const float*)d_in[14];
    const int* src   = (const int*)d_in[15];
    const int* dst   = (const int*)d_in[16];
    float* out = (float*)d_out;

    // workspace layout
    float* h8     = (float*)d_ws;            // N*D (slice-major)
    float* act    = h8 + (size_t)N * D;      // N*D (standard row-major)
    float* dinv   = act + (size_t)N * D;     // N
    int* cnt      = (int*)(dinv + N);        // N
    int* row_ptr  = cnt + N;                 // N+1
    int* esrc     = row_ptr + (N + 2);       // E
    float* scale1 = (float*)(esrc + E);      // 128
    float* shift1 = scale1 + D;
    float* scale2 = shift1 + D;
    float* shift2 = scale2 + D;
    int* bsum     = (int*)(shift2 + D);      // 64
    int* boff     = bsum + 64;               // 64

    const int NB = (N + 1023) / 1024;  // 49 scan blocks

    // ---- CSR build (reused by all 3 layers); dinv needed before mm1
    zero_kernel<<<(N + 255) / 256, 256, 0, stream>>>(cnt, N);
    hist_kernel<<<(E + 255) / 256, 256, 0, stream>>>(dst, cnt, E);
    block_reduce<<<NB, 256, 0, stream>>>(cnt, bsum, N);
    scan_bsums<<<1, 64, 0, stream>>>(bsum, boff, NB, &row_ptr[N]);
    scan_apply<<<NB, 256, 0, stream>>>(cnt, boff, row_ptr, dinv, cnt, N);
    fill_kernel<<<(E + 255) / 256, 256, 0, stream>>>(src, dst, row_ptr, cnt, esrc, E);
    prep_kernel<<<1, D, 0, stream>>>(b1, g1, be1, m1, v1, scale1, shift1);
    prep_kernel<<<1, D, 0, stream>>>(b2, g2, be2, m2, v2, scale2, shift2);

    int mm_grid = (N + 63) / 64;
    int agg_grid = ((N + 3) / 4) * 8;   // x8 slices

    // ---- layer 1
    mm_kernel<<<mm_grid, 256, 0, stream>>>(x, W1, dinv, h8, N);
    agg_kernel<0><<<agg_grid, 256, 0, stream>>>(h8, row_ptr, esrc, dinv,
                                                scale1, shift1, nullptr, act, N);
    // ---- layer 2
    mm_kernel<<<mm_grid, 256, 0, stream>>>(act, W2, dinv, h8, N);
    agg_kernel<0><<<agg_grid, 256, 0, stream>>>(h8, row_ptr, esrc, dinv,
                                                scale2, shift2, nullptr, act, N);
    // ---- layer 3 (+bias +residual, writes d_out)
    mm_kernel<<<mm_grid, 256, 0, stream>>>(act, W3, dinv, h8, N);
    agg_kernel<1><<<agg_grid, 256, 0, stream>>>(h8, row_ptr, esrc, dinv,
                                                b3, nullptr, x, out, N);
}

// Round 10
// 418.664 us; speedup vs baseline: 1.6724x; 1.6724x over previous
//
#include <hip/hip_runtime.h>
#include <hip/hip_bf16.h>

// GCN 3-layer: GCNConv -> BN -> ReLU (x2) -> GCNConv -> +residual
// N=50000, E=800000, D=128, fp32 in/out.
//
// Round 10: revert XCD slice-major (round 9: FETCH 202->81MB but dur 65->148us;
// slicing killed MLP + split gathers into 64B fragments). Back to round-3 shape
// (wave = node, full 128ch, contiguous row gather, deep unroll) with the bytes
// halved instead: mm epilogue writes h' = dinv*(A@W) as BF16 rows (256B), agg
// gathers bf16x2 per lane, 8 edges in flight, fp32 accumulate.

#define GCN_N 50000
#define GCN_E 800000
#define GCN_D 128

// bf16 helpers (bit ops; values are finite, no NaN path needed)
__device__ __forceinline__ float bflo(unsigned u) { return __uint_as_float(u << 16); }
__device__ __forceinline__ float bfhi(unsigned u) { return __uint_as_float(u & 0xffff0000u); }
__device__ __forceinline__ unsigned f2bf(float f) {          // round-to-nearest-even
    unsigned u = __float_as_uint(f);
    return (u + 0x7fffu + ((u >> 16) & 1u)) >> 16;
}

// ---------------------------------------------------------------- zero int buf
__global__ __launch_bounds__(256) void zero_kernel(int* __restrict__ p, int n) {
    int i = blockIdx.x * blockDim.x + threadIdx.x;
    if (i < n) p[i] = 0;
}

// ---------------------------------------------------------------- histogram
__global__ __launch_bounds__(256) void hist_kernel(const int* __restrict__ dst,
                                                   int* __restrict__ cnt, int nE) {
    int e = blockIdx.x * blockDim.x + threadIdx.x;
    if (e < nE) atomicAdd(&cnt[dst[e]], 1);
}

// ------------------------------------------------- multi-block prefix sum
__global__ __launch_bounds__(256) void block_reduce(const int* __restrict__ cnt,
                                                    int* __restrict__ bsum, int n) {
    int tid = threadIdx.x, lane = tid & 63, wid = tid >> 6;
    int i0 = blockIdx.x * 1024 + tid * 4;
    int s = 0;
    #pragma unroll
    for (int q = 0; q < 4; ++q)
        if (i0 + q < n) s += cnt[i0 + q];
    #pragma unroll
    for (int off = 32; off >= 1; off >>= 1) s += __shfl_xor(s, off);
    __shared__ int ws[4];
    if (lane == 0) ws[wid] = s;
    __syncthreads();
    if (tid == 0) bsum[blockIdx.x] = ws[0] + ws[1] + ws[2] + ws[3];
}

__global__ void scan_bsums(const int* __restrict__ bsum, int* __restrict__ boff,
                           int nb, int* __restrict__ row_last) {
    int lane = threadIdx.x;  // 64 threads
    int v = (lane < nb) ? bsum[lane] : 0;
    int sc = v;
    #pragma unroll
    for (int off = 1; off < 64; off <<= 1) {
        int t = __shfl_up(sc, off);
        if (lane >= off) sc += t;
    }
    if (lane < nb) boff[lane] = sc - v;
    if (lane == 63) *row_last = sc;  // row_ptr[N] = E
}

// row_ptr (exclusive scan), dinv = rsqrt(deg+1), zero cnt for fill cursor.
__global__ __launch_bounds__(256) void scan_apply(const int* __restrict__ cnt_in,
                                                  const int* __restrict__ boff,
                                                  int* __restrict__ row_ptr,
                                                  float* __restrict__ dinv,
                                                  int* __restrict__ cnt_zero, int n) {
    __shared__ int wsum[4];
    int tid = threadIdx.x, lane = tid & 63, wid = tid >> 6;
    int i0 = blockIdx.x * 1024 + tid * 4;
    int a0 = 0, a1 = 0, a2 = 0, a3 = 0;
    if (i0 + 0 < n) a0 = cnt_in[i0 + 0];
    if (i0 + 1 < n) a1 = cnt_in[i0 + 1];
    if (i0 + 2 < n) a2 = cnt_in[i0 + 2];
    if (i0 + 3 < n) a3 = cnt_in[i0 + 3];
    int tsum = a0 + a1 + a2 + a3;
    int sc = tsum;
    #pragma unroll
    for (int off = 1; off < 64; off <<= 1) {
        int t = __shfl_up(sc, off);
        if (lane >= off) sc += t;
    }
    if (lane == 63) wsum[wid] = sc;
    __syncthreads();
    int woff = 0;
    #pragma unroll
    for (int w = 0; w < 4; ++w)
        if (w < wid) woff += wsum[w];
    int excl = boff[blockIdx.x] + woff + (sc - tsum);
    if (i0 + 0 < n) { row_ptr[i0 + 0] = excl;                dinv[i0 + 0] = rsqrtf((float)a0 + 1.f); cnt_zero[i0 + 0] = 0; }
    if (i0 + 1 < n) { row_ptr[i0 + 1] = excl + a0;           dinv[i0 + 1] = rsqrtf((float)a1 + 1.f); cnt_zero[i0 + 1] = 0; }
    if (i0 + 2 < n) { row_ptr[i0 + 2] = excl + a0 + a1;      dinv[i0 + 2] = rsqrtf((float)a2 + 1.f); cnt_zero[i0 + 2] = 0; }
    if (i0 + 3 < n) { row_ptr[i0 + 3] = excl + a0 + a1 + a2; dinv[i0 + 3] = rsqrtf((float)a3 + 1.f); cnt_zero[i0 + 3] = 0; }
}

// ---------------------------------------------------------------- CSR fill
__global__ __launch_bounds__(256) void fill_kernel(const int* __restrict__ src,
                                                   const int* __restrict__ dst,
                                                   const int* __restrict__ row_ptr,
                                                   int* __restrict__ cur,
                                                   int* __restrict__ esrc, int nE) {
    int e = blockIdx.x * blockDim.x + threadIdx.x;
    if (e >= nE) return;
    int d = dst[e];
    int pos = row_ptr[d] + atomicAdd(&cur[d], 1);
    esrc[pos] = src[e];
}

// ------------------------------------------------- fold BN into scale/shift
__global__ void prep_kernel(const float* __restrict__ b, const float* __restrict__ g,
                            const float* __restrict__ be, const float* __restrict__ m,
                            const float* __restrict__ v, float* __restrict__ scale,
                            float* __restrict__ shift) {
    int c = threadIdx.x;
    float s = g[c] * rsqrtf(v[c] + 1e-5f);
    scale[c] = s;
    shift[c] = (b[c] - m[c]) * s + be[c];
}

// ---------------------------------------------------------------- matmul
// hb[node][128] (bf16) = dinv[node] * (A[node,:] @ W)
// Block: 256 threads (16x16), tile 64 rows x 128 cols, BK=64, per-thread 4x8.
// Core loop identical to the round-3-verified version; epilogue packs bf16.
__global__ __launch_bounds__(256) void mm_kernel(const float* __restrict__ A,
                                                 const float* __restrict__ W,
                                                 const float* __restrict__ dinv,
                                                 unsigned short* __restrict__ hb, int n) {
    __shared__ float As[64][68];
    __shared__ float Bs[64][132];
    int tid = threadIdx.x;
    int tx = tid & 15;
    int ty = tid >> 4;
    int row0 = blockIdx.x * 64;
    float acc[4][8] = {};

    for (int k0 = 0; k0 < 128; k0 += 64) {
        int ac = (tid & 15) * 4;
        int ar = tid >> 4;
        #pragma unroll
        for (int rr = 0; rr < 4; ++rr) {
            int r = ar + rr * 16;
            int gr = row0 + r;
            float4 v = make_float4(0.f, 0.f, 0.f, 0.f);
            if (gr < n) v = *(const float4*)&A[(size_t)gr * GCN_D + k0 + ac];
            *(float4*)&As[r][ac] = v;
        }
        int bc = (tid & 31) * 4;
        int br = tid >> 5;
        #pragma unroll
        for (int rr = 0; rr < 8; ++rr) {
            int r = br + rr * 8;
            float4 v = *(const float4*)&W[(size_t)(k0 + r) * GCN_D + bc];
            *(float4*)&Bs[r][bc] = v;
        }
        __syncthreads();
        #pragma unroll
        for (int kk = 0; kk < 64; ++kk) {
            float a[4];
            #pragma unroll
            for (int m = 0; m < 4; ++m) a[m] = As[ty * 4 + m][kk];
            float4 b0 = *(const float4*)&Bs[kk][tx * 8];
            float4 b1 = *(const float4*)&Bs[kk][tx * 8 + 4];
            float b[8] = {b0.x, b0.y, b0.z, b0.w, b1.x, b1.y, b1.z, b1.w};
            #pragma unroll
            for (int m = 0; m < 4; ++m)
                #pragma unroll
                for (int q = 0; q < 8; ++q) acc[m][q] += a[m] * b[q];
        }
        __syncthreads();
    }
    // epilogue: scale by dinv, pack bf16 (rne), one 16B store per thread-row
    #pragma unroll
    for (int m = 0; m < 4; ++m) {
        int gr = row0 + ty * 4 + m;
        if (gr < n) {
            float dv = dinv[gr];
            unsigned w0 = f2bf(acc[m][0] * dv) | (f2bf(acc[m][1] * dv) << 16);
            unsigned w1 = f2bf(acc[m][2] * dv) | (f2bf(acc[m][3] * dv) << 16);
            unsigned w2 = f2bf(acc[m][4] * dv) | (f2bf(acc[m][5] * dv) << 16);
            unsigned w3 = f2bf(acc[m][6] * dv) | (f2bf(acc[m][7] * dv) << 16);
            *(uint4*)&hb[(size_t)gr * GCN_D + tx * 8] = make_uint4(w0, w1, w2, w3);
        }
    }
}

// ------------------------------------------------- fused aggregate + epilogue
// Wave = one node, lane owns channels (2*lane, 2*lane+1): per edge one bf16x2
// (4B) load per lane -> 256B contiguous per edge row; 8 edges in flight.
// out = dinv[dst]*(h'[dst] + sum h'[src]);  h' already carries dinv[src].
// FINAL=0: out = relu(v*scale + shift); FINAL=1: out = v + b3 + xres.
template <int FINAL>
__global__ __launch_bounds__(256) void agg_kernel(const unsigned short* __restrict__ hb,
                                                  const int* __restrict__ row_ptr,
                                                  const int* __restrict__ esrc,
                                                  const float* __restrict__ dinv,
                                                  const float* __restrict__ scale,
                                                  const float* __restrict__ shift,
                                                  const float* __restrict__ xres,
                                                  float* __restrict__ out, int n) {
    int wid = threadIdx.x >> 6, lane = threadIdx.x & 63;
    int node = blockIdx.x * 4 + wid;
    if (node >= n) return;
    int cc = lane * 2;  // channel pair
    unsigned us = *(const unsigned*)&hb[(size_t)node * GCN_D + cc];
    float aLo = bflo(us), aHi = bfhi(us);   // self term h'[dst]
    float bLo = 0.f, bHi = 0.f;
    int j = row_ptr[node], end = row_ptr[node + 1];
    for (; j + 8 <= end; j += 8) {
        int s0 = esrc[j + 0], s1 = esrc[j + 1], s2 = esrc[j + 2], s3 = esrc[j + 3];
        int s4 = esrc[j + 4], s5 = esrc[j + 5], s6 = esrc[j + 6], s7 = esrc[j + 7];
        unsigned u0 = *(const unsigned*)&hb[(size_t)s0 * GCN_D + cc];
        unsigned u1 = *(const unsigned*)&hb[(size_t)s1 * GCN_D + cc];
        unsigned u2 = *(const unsigned*)&hb[(size_t)s2 * GCN_D + cc];
        unsigned u3 = *(const unsigned*)&hb[(size_t)s3 * GCN_D + cc];
        unsigned u4 = *(const unsigned*)&hb[(size_t)s4 * GCN_D + cc];
        unsigned u5 = *(const unsigned*)&hb[(size_t)s5 * GCN_D + cc];
        unsigned u6 = *(const unsigned*)&hb[(size_t)s6 * GCN_D + cc];
        unsigned u7 = *(const unsigned*)&hb[(size_t)s7 * GCN_D + cc];
        aLo += bflo(u0) + bflo(u1);  aHi += bfhi(u0) + bfhi(u1);
        bLo += bflo(u2) + bflo(u3);  bHi += bfhi(u2) + bfhi(u3);
        aLo += bflo(u4) + bflo(u5);  aHi += bfhi(u4) + bfhi(u5);
        bLo += bflo(u6) + bflo(u7);  bHi += bfhi(u6) + bfhi(u7);
    }
    for (; j < end; ++j) {
        int s = esrc[j];
        unsigned u = *(const unsigned*)&hb[(size_t)s * GCN_D + cc];
        aLo += bflo(u);  aHi += bfhi(u);
    }
    float dvn = dinv[node];
    float vx = (aLo + bLo) * dvn;
    float vy = (aHi + bHi) * dvn;
    float2 o;
    if (FINAL) {
        float2 b = *(const float2*)&scale[cc];   // b3 passed via 'scale'
        float2 xr = *(const float2*)&xres[(size_t)node * GCN_D + cc];
        o.x = vx + b.x + xr.x;
        o.y = vy + b.y + xr.y;
    } else {
        float2 sc = *(const float2*)&scale[cc];
        float2 sh = *(const float2*)&shift[cc];
        o.x = fmaxf(vx * sc.x + sh.x, 0.f);
        o.y = fmaxf(vy * sc.y + sh.y, 0.f);
    }
    *(float2*)&out[(size_t)node * GCN_D + cc] = o;
}

// ---------------------------------------------------------------- launch
extern "C" void kernel_launch(void* const* d_in, const int* in_sizes, int n_in,
                              void* d_out, int out_size, void* d_ws, size_t ws_size,
                              hipStream_t stream) {
    (void)in_sizes; (void)n_in; (void)out_size; (void)ws_size;
    const int N = GCN_N, E = GCN_E, D = GCN_D;

    const float* x   = (const float*)d_in[0];
    const float* W1  = (const float*)d_in[1];
    const float* b1  = (const float*)d_in[2];
    const float* g1  = (const float*)d_in[3];
    const float* be1 = (const float*)d_in[4];
    const float* m1  = (const float*)d_in[5];
    const float* v1  = (const float*)d_in[6];
    const float* W2  = (const float*)d_in[7];
    const float* b2  = (const float*)d_in[8];
    const float* g2  = (const float*)d_in[9];
    const float* be2 = (const float*)d_in[10];
    const float* m2  = (const float*)d_in[11];
    const float* v2  = (const float*)d_in[12];
    const float* W3  = (const float*)d_in[13];
    const float* b3  = (const float*)d_in[14];
    const int* src   = (const int*)d_in[15];
    const int* dst   = (const int*)d_in[16];
    float* out = (float*)d_out;

    // workspace layout
    unsigned short* hb = (unsigned short*)d_ws;        // N*D bf16 (12.8MB)
    float* act    = (float*)(hb + (size_t)N * D);      // N*D fp32
    float* dinv   = act + (size_t)N * D;               // N
    int* cnt      = (int*)(dinv + N);                  // N
    int* row_ptr  = cnt + N;                           // N+1
    int* esrc     = row_ptr + (N + 2);                 // E
    float* scale1 = (float*)(esrc + E);                // 128
    float* shift1 = scale1 + D;
    float* scale2 = shift1 + D;
    float* shift2 = scale2 + D;
    int* bsum     = (int*)(shift2 + D);                // 64
    int* boff     = bsum + 64;                         // 64

    const int NB = (N + 1023) / 1024;  // 49 scan blocks

    // ---- CSR build (reused by all 3 layers); dinv needed before mm1
    zero_kernel<<<(N + 255) / 256, 256, 0, stream>>>(cnt, N);
    hist_kernel<<<(E + 255) / 256, 256, 0, stream>>>(dst, cnt, E);
    block_reduce<<<NB, 256, 0, stream>>>(cnt, bsum, N);
    scan_bsums<<<1, 64, 0, stream>>>(bsum, boff, NB, &row_ptr[N]);
    scan_apply<<<NB, 256, 0, stream>>>(cnt, boff, row_ptr, dinv, cnt, N);
    fill_kernel<<<(E + 255) / 256, 256, 0, stream>>>(src, dst, row_ptr, cnt, esrc, E);
    prep_kernel<<<1, D, 0, stream>>>(b1, g1, be1, m1, v1, scale1, shift1);
    prep_kernel<<<1, D, 0, stream>>>(b2, g2, be2, m2, v2, scale2, shift2);

    int mm_grid = (N + 63) / 64;
    int agg_grid = (N + 3) / 4;

    // ---- layer 1
    mm_kernel<<<mm_grid, 256, 0, stream>>>(x, W1, dinv, hb, N);
    agg_kernel<0><<<agg_grid, 256, 0, stream>>>(hb, row_ptr, esrc, dinv,
                                                scale1, shift1, nullptr, act, N);
    // ---- layer 2
    mm_kernel<<<mm_grid, 256, 0, stream>>>(act, W2, dinv, hb, N);
    agg_kernel<0><<<agg_grid, 256, 0, stream>>>(hb, row_ptr, esrc, dinv,
                                                scale2, shift2, nullptr, act, N);
    // ---- layer 3 (+bias +residual, writes d_out)
    mm_kernel<<<mm_grid, 256, 0, stream>>>(act, W3, dinv, hb, N);
    agg_kernel<1><<<agg_grid, 256, 0, stream>>>(hb, row_ptr, esrc, dinv,
                                                b3, nullptr, x, out, N);
}

// Round 11
// 392.965 us; speedup vs baseline: 1.7817x; 1.0654x over previous
//
#include <hip/hip_runtime.h>
#include <hip/hip_bf16.h>

// GCN 3-layer: GCNConv -> BN -> ReLU (x2) -> GCNConv -> +residual
// N=50000, E=800000, D=128, fp32 in/out.
//
// Round 11: bf16 MFMA datapath.
//   - mm: v_mfma_f32_16x16x32_bf16; A (bf16 act) frags loaded direct from
//     global (full-line pattern), B from pre-transposed bf16 Wt (L1-resident);
//     epilogue dinv-scale + bf16 pack + LDS transpose -> coalesced stores.
//   - agg<0> writes bf16 act (u32-packed pair per lane) for the next mm;
//     agg<1> writes fp32 d_out (+b3+residual). Gather loop = round-10 verified.
//   - x->bf16 cast and W->Wt^T bf16 prep kernels (tiny, once per launch).
//   - fill/hist untouched this round (fill = next target, 46us scatter-bound).

#define GCN_N 50000
#define GCN_E 800000
#define GCN_D 128

using bf16x8 = __attribute__((ext_vector_type(8))) short;
using f32x4  = __attribute__((ext_vector_type(4))) float;

// bf16 helpers (bit ops; finite values only)
__device__ __forceinline__ float bflo(unsigned u) { return __uint_as_float(u << 16); }
__device__ __forceinline__ float bfhi(unsigned u) { return __uint_as_float(u & 0xffff0000u); }
__device__ __forceinline__ unsigned f2bf(float f) {          // round-to-nearest-even
    unsigned u = __float_as_uint(f);
    return (u + 0x7fffu + ((u >> 16) & 1u)) >> 16;
}

// ---------------------------------------------------------------- zero int buf
__global__ __launch_bounds__(256) void zero_kernel(int* __restrict__ p, int n) {
    int i = blockIdx.x * blockDim.x + threadIdx.x;
    if (i < n) p[i] = 0;
}

// ---------------------------------------------------------------- histogram
__global__ __launch_bounds__(256) void hist_kernel(const int* __restrict__ dst,
                                                   int* __restrict__ cnt, int nE) {
    int e = blockIdx.x * blockDim.x + threadIdx.x;
    if (e < nE) atomicAdd(&cnt[dst[e]], 1);
}

// ------------------------------------------------- multi-block prefix sum
__global__ __launch_bounds__(256) void block_reduce(const int* __restrict__ cnt,
                                                    int* __restrict__ bsum, int n) {
    int tid = threadIdx.x, lane = tid & 63, wid = tid >> 6;
    int i0 = blockIdx.x * 1024 + tid * 4;
    int s = 0;
    #pragma unroll
    for (int q = 0; q < 4; ++q)
        if (i0 + q < n) s += cnt[i0 + q];
    #pragma unroll
    for (int off = 32; off >= 1; off >>= 1) s += __shfl_xor(s, off);
    __shared__ int ws[4];
    if (lane == 0) ws[wid] = s;
    __syncthreads();
    if (tid == 0) bsum[blockIdx.x] = ws[0] + ws[1] + ws[2] + ws[3];
}

__global__ void scan_bsums(const int* __restrict__ bsum, int* __restrict__ boff,
                           int nb, int* __restrict__ row_last) {
    int lane = threadIdx.x;  // 64 threads
    int v = (lane < nb) ? bsum[lane] : 0;
    int sc = v;
    #pragma unroll
    for (int off = 1; off < 64; off <<= 1) {
        int t = __shfl_up(sc, off);
        if (lane >= off) sc += t;
    }
    if (lane < nb) boff[lane] = sc - v;
    if (lane == 63) *row_last = sc;  // row_ptr[N] = E
}

// row_ptr (exclusive scan), dinv = rsqrt(deg+1), zero cnt for fill cursor.
__global__ __launch_bounds__(256) void scan_apply(const int* __restrict__ cnt_in,
                                                  const int* __restrict__ boff,
                                                  int* __restrict__ row_ptr,
                                                  float* __restrict__ dinv,
                                                  int* __restrict__ cnt_zero, int n) {
    __shared__ int wsum[4];
    int tid = threadIdx.x, lane = tid & 63, wid = tid >> 6;
    int i0 = blockIdx.x * 1024 + tid * 4;
    int a0 = 0, a1 = 0, a2 = 0, a3 = 0;
    if (i0 + 0 < n) a0 = cnt_in[i0 + 0];
    if (i0 + 1 < n) a1 = cnt_in[i0 + 1];
    if (i0 + 2 < n) a2 = cnt_in[i0 + 2];
    if (i0 + 3 < n) a3 = cnt_in[i0 + 3];
    int tsum = a0 + a1 + a2 + a3;
    int sc = tsum;
    #pragma unroll
    for (int off = 1; off < 64; off <<= 1) {
        int t = __shfl_up(sc, off);
        if (lane >= off) sc += t;
    }
    if (lane == 63) wsum[wid] = sc;
    __syncthreads();
    int woff = 0;
    #pragma unroll
    for (int w = 0; w < 4; ++w)
        if (w < wid) woff += wsum[w];
    int excl = boff[blockIdx.x] + woff + (sc - tsum);
    if (i0 + 0 < n) { row_ptr[i0 + 0] = excl;                dinv[i0 + 0] = rsqrtf((float)a0 + 1.f); cnt_zero[i0 + 0] = 0; }
    if (i0 + 1 < n) { row_ptr[i0 + 1] = excl + a0;           dinv[i0 + 1] = rsqrtf((float)a1 + 1.f); cnt_zero[i0 + 1] = 0; }
    if (i0 + 2 < n) { row_ptr[i0 + 2] = excl + a0 + a1;      dinv[i0 + 2] = rsqrtf((float)a2 + 1.f); cnt_zero[i0 + 2] = 0; }
    if (i0 + 3 < n) { row_ptr[i0 + 3] = excl + a0 + a1 + a2; dinv[i0 + 3] = rsqrtf((float)a3 + 1.f); cnt_zero[i0 + 3] = 0; }
}

// ---------------------------------------------------------------- CSR fill
__global__ __launch_bounds__(256) void fill_kernel(const int* __restrict__ src,
                                                   const int* __restrict__ dst,
                                                   const int* __restrict__ row_ptr,
                                                   int* __restrict__ cur,
                                                   int* __restrict__ esrc, int nE) {
    int e = blockIdx.x * blockDim.x + threadIdx.x;
    if (e >= nE) return;
    int d = dst[e];
    int pos = row_ptr[d] + atomicAdd(&cur[d], 1);
    esrc[pos] = src[e];
}

// ------------------------------------------------- fold BN into scale/shift
__global__ void prep_kernel(const float* __restrict__ b, const float* __restrict__ g,
                            const float* __restrict__ be, const float* __restrict__ m,
                            const float* __restrict__ v, float* __restrict__ scale,
                            float* __restrict__ shift) {
    int c = threadIdx.x;
    float s = g[c] * rsqrtf(v[c] + 1e-5f);
    scale[c] = s;
    shift[c] = (b[c] - m[c]) * s + be[c];
}

// ------------------------------------------------- x -> bf16 cast (6.4M elems)
__global__ __launch_bounds__(256) void castx_kernel(const float* __restrict__ x,
                                                    unsigned short* __restrict__ xb,
                                                    int nElem) {
    int i = (blockIdx.x * 256 + threadIdx.x) * 8;
    if (i + 7 < nElem) {
        float4 f0 = *(const float4*)&x[i];
        float4 f1 = *(const float4*)&x[i + 4];
        uint4 o;
        o.x = f2bf(f0.x) | (f2bf(f0.y) << 16);
        o.y = f2bf(f0.z) | (f2bf(f0.w) << 16);
        o.z = f2bf(f1.x) | (f2bf(f1.y) << 16);
        o.w = f2bf(f1.z) | (f2bf(f1.w) << 16);
        *(uint4*)&xb[i] = o;
    }
}

// ------------------------------------------------- W[k][n] -> Wt[n][k] bf16
__global__ __launch_bounds__(256) void wtrans_kernel(const float* __restrict__ W,
                                                     unsigned short* __restrict__ Wt) {
    int id = blockIdx.x * 256 + threadIdx.x;  // 16384
    int nn = id >> 7, k = id & 127;
    Wt[id] = (unsigned short)f2bf(W[k * 128 + nn]);
}

// ---------------------------------------------------------------- MFMA matmul
// hb[node][128] (bf16) = dinv[node] * (A[node,:] @ W);  A bf16, Wt = W^T bf16.
// 4 waves/block; wave w owns rows [row0+16w, +16) x 128 cols = 8 tiles x 4 K.
// A/B frags direct from global (16B/lane, full-line). C/D map (verified):
// col=lane&15, row=(lane>>4)*4+reg. Epilogue via LDS for coalesced bf16 rows.
__global__ __launch_bounds__(256) void mm_mfma(const unsigned short* __restrict__ A,
                                               const unsigned short* __restrict__ Wt,
                                               const float* __restrict__ dinv,
                                               unsigned short* __restrict__ hb, int n) {
    __shared__ unsigned short Cs[64][136];   // pad to 272B stride
    int tid = threadIdx.x;
    int w = tid >> 6, l = tid & 63;
    int lg = l >> 4, li = l & 15;
    int row0 = blockIdx.x * 64;

    int arow = row0 + w * 16 + li;
    int arow_c = min(arow, n - 1);
    const unsigned short* ap = A + (size_t)arow_c * GCN_D + lg * 8;
    bf16x8 a[4];
    #pragma unroll
    for (int k0 = 0; k0 < 4; ++k0) a[k0] = *(const bf16x8*)(ap + k0 * 32);

    f32x4 acc[8];
    #pragma unroll
    for (int t = 0; t < 8; ++t) acc[t] = (f32x4){0.f, 0.f, 0.f, 0.f};

    #pragma unroll
    for (int t = 0; t < 8; ++t) {
        const unsigned short* bp = Wt + (size_t)(t * 16 + li) * GCN_D + lg * 8;
        #pragma unroll
        for (int k0 = 0; k0 < 4; ++k0) {
            bf16x8 b = *(const bf16x8*)(bp + k0 * 32);
            acc[t] = __builtin_amdgcn_mfma_f32_16x16x32_bf16(a[k0], b, acc[t], 0, 0, 0);
        }
    }

    // epilogue: scale by dinv, pack bf16, stage in LDS
    int crow = w * 16 + lg * 4;
    float dv[4];
    #pragma unroll
    for (int r = 0; r < 4; ++r) dv[r] = dinv[min(row0 + crow + r, n - 1)];
    #pragma unroll
    for (int t = 0; t < 8; ++t)
        #pragma unroll
        for (int r = 0; r < 4; ++r)
            Cs[crow + r][t * 16 + li] = (unsigned short)f2bf(acc[t][r] * dv[r]);
    __syncthreads();

    // coalesced store: thread -> row tid>>2, 32-col chunk tid&3
    int orow = tid >> 2;
    int gr = row0 + orow;
    if (gr < n) {
        const unsigned short* sp = &Cs[orow][(tid & 3) * 32];
        uint4* dp = (uint4*)&hb[(size_t)gr * GCN_D + (tid & 3) * 32];
        dp[0] = *(const uint4*)(sp + 0);
        dp[1] = *(const uint4*)(sp + 8);
        dp[2] = *(const uint4*)(sp + 16);
        dp[3] = *(const uint4*)(sp + 24);
    }
}

// ------------------------------------------------- fused aggregate + epilogue
// Wave = one node, lane owns channel pair; bf16x2 (4B) gather per lane per
// edge; 8 edges in flight; fp32 accumulate. (round-10 verified loop)
// FINAL=0: outb (bf16) = relu(v*scale+shift); FINAL=1: outf (fp32) = v+b3+xres.
template <int FINAL>
__global__ __launch_bounds__(256) void agg_kernel(const unsigned short* __restrict__ hb,
                                                  const int* __restrict__ row_ptr,
                                                  const int* __restrict__ esrc,
                                                  const float* __restrict__ dinv,
                                                  const float* __restrict__ scale,
                                                  const float* __restrict__ shift,
                                                  const float* __restrict__ xres,
                                                  unsigned short* __restrict__ outb,
                                                  float* __restrict__ outf, int n) {
    int wid = threadIdx.x >> 6, lane = threadIdx.x & 63;
    int node = blockIdx.x * 4 + wid;
    if (node >= n) return;
    int cc = lane * 2;  // channel pair
    unsigned us = *(const unsigned*)&hb[(size_t)node * GCN_D + cc];
    float aLo = bflo(us), aHi = bfhi(us);   // self term h'[dst]
    float bLo = 0.f, bHi = 0.f;
    int j = row_ptr[node], end = row_ptr[node + 1];
    for (; j + 8 <= end; j += 8) {
        int s0 = esrc[j + 0], s1 = esrc[j + 1], s2 = esrc[j + 2], s3 = esrc[j + 3];
        int s4 = esrc[j + 4], s5 = esrc[j + 5], s6 = esrc[j + 6], s7 = esrc[j + 7];
        unsigned u0 = *(const unsigned*)&hb[(size_t)s0 * GCN_D + cc];
        unsigned u1 = *(const unsigned*)&hb[(size_t)s1 * GCN_D + cc];
        unsigned u2 = *(const unsigned*)&hb[(size_t)s2 * GCN_D + cc];
        unsigned u3 = *(const unsigned*)&hb[(size_t)s3 * GCN_D + cc];
        unsigned u4 = *(const unsigned*)&hb[(size_t)s4 * GCN_D + cc];
        unsigned u5 = *(const unsigned*)&hb[(size_t)s5 * GCN_D + cc];
        unsigned u6 = *(const unsigned*)&hb[(size_t)s6 * GCN_D + cc];
        unsigned u7 = *(const unsigned*)&hb[(size_t)s7 * GCN_D + cc];
        aLo += bflo(u0) + bflo(u1);  aHi += bfhi(u0) + bfhi(u1);
        bLo += bflo(u2) + bflo(u3);  bHi += bfhi(u2) + bfhi(u3);
        aLo += bflo(u4) + bflo(u5);  aHi += bfhi(u4) + bfhi(u5);
        bLo += bflo(u6) + bflo(u7);  bHi += bfhi(u6) + bfhi(u7);
    }
    for (; j < end; ++j) {
        int s = esrc[j];
        unsigned u = *(const unsigned*)&hb[(size_t)s * GCN_D + cc];
        aLo += bflo(u);  aHi += bfhi(u);
    }
    float dvn = dinv[node];
    float vx = (aLo + bLo) * dvn;
    float vy = (aHi + bHi) * dvn;
    if (FINAL) {
        float2 b = *(const float2*)&scale[cc];   // b3 passed via 'scale'
        float2 xr = *(const float2*)&xres[(size_t)node * GCN_D + cc];
        float2 o;
        o.x = vx + b.x + xr.x;
        o.y = vy + b.y + xr.y;
        *(float2*)&outf[(size_t)node * GCN_D + cc] = o;
    } else {
        float2 sc = *(const float2*)&scale[cc];
        float2 sh = *(const float2*)&shift[cc];
        float ox = fmaxf(vx * sc.x + sh.x, 0.f);
        float oy = fmaxf(vy * sc.y + sh.y, 0.f);
        *(unsigned*)&outb[(size_t)node * GCN_D + cc] = f2bf(ox) | (f2bf(oy) << 16);
    }
}

// ---------------------------------------------------------------- launch
extern "C" void kernel_launch(void* const* d_in, const int* in_sizes, int n_in,
                              void* d_out, int out_size, void* d_ws, size_t ws_size,
                              hipStream_t stream) {
    (void)in_sizes; (void)n_in; (void)out_size; (void)ws_size;
    const int N = GCN_N, E = GCN_E, D = GCN_D;

    const float* x   = (const float*)d_in[0];
    const float* W1  = (const float*)d_in[1];
    const float* b1  = (const float*)d_in[2];
    const float* g1  = (const float*)d_in[3];
    const float* be1 = (const float*)d_in[4];
    const float* m1  = (const float*)d_in[5];
    const float* v1  = (const float*)d_in[6];
    const float* W2  = (const float*)d_in[7];
    const float* b2  = (const float*)d_in[8];
    const float* g2  = (const float*)d_in[9];
    const float* be2 = (const float*)d_in[10];
    const float* m2  = (const float*)d_in[11];
    const float* v2  = (const float*)d_in[12];
    const float* W3  = (const float*)d_in[13];
    const float* b3  = (const float*)d_in[14];
    const int* src   = (const int*)d_in[15];
    const int* dst   = (const int*)d_in[16];
    float* out = (float*)d_out;

    // workspace layout (bf16 buffers first, then 4B-typed)
    unsigned short* hb   = (unsigned short*)d_ws;        // N*D bf16
    unsigned short* actb = hb + (size_t)N * D;           // N*D bf16
    unsigned short* xb   = actb + (size_t)N * D;         // N*D bf16
    unsigned short* wt1  = xb + (size_t)N * D;           // 16384
    unsigned short* wt2  = wt1 + D * D;
    unsigned short* wt3  = wt2 + D * D;
    float* dinv   = (float*)(wt3 + D * D);               // N  (even shorts so far)
    int* cnt      = (int*)(dinv + N);                    // N
    int* row_ptr  = cnt + N;                             // N+1
    int* esrc     = row_ptr + (N + 2);                   // E
    float* scale1 = (float*)(esrc + E);                  // 128
    float* shift1 = scale1 + D;
    float* scale2 = shift1 + D;
    float* shift2 = scale2 + D;
    int* bsum     = (int*)(shift2 + D);                  // 64
    int* boff     = bsum + 64;                           // 64

    const int NB = (N + 1023) / 1024;  // 49 scan blocks

    // ---- one-time prep: casts + transposes + CSR build
    castx_kernel<<<(N * D) / (256 * 8), 256, 0, stream>>>(x, xb, N * D);
    wtrans_kernel<<<(D * D) / 256, 256, 0, stream>>>(W1, wt1);
    wtrans_kernel<<<(D * D) / 256, 256, 0, stream>>>(W2, wt2);
    wtrans_kernel<<<(D * D) / 256, 256, 0, stream>>>(W3, wt3);
    zero_kernel<<<(N + 255) / 256, 256, 0, stream>>>(cnt, N);
    hist_kernel<<<(E + 255) / 256, 256, 0, stream>>>(dst, cnt, E);
    block_reduce<<<NB, 256, 0, stream>>>(cnt, bsum, N);
    scan_bsums<<<1, 64, 0, stream>>>(bsum, boff, NB, &row_ptr[N]);
    scan_apply<<<NB, 256, 0, stream>>>(cnt, boff, row_ptr, dinv, cnt, N);
    fill_kernel<<<(E + 255) / 256, 256, 0, stream>>>(src, dst, row_ptr, cnt, esrc, E);
    prep_kernel<<<1, D, 0, stream>>>(b1, g1, be1, m1, v1, scale1, shift1);
    prep_kernel<<<1, D, 0, stream>>>(b2, g2, be2, m2, v2, scale2, shift2);

    int mm_grid = (N + 63) / 64;
    int agg_grid = (N + 3) / 4;

    // ---- layer 1
    mm_mfma<<<mm_grid, 256, 0, stream>>>(xb, wt1, dinv, hb, N);
    agg_kernel<0><<<agg_grid, 256, 0, stream>>>(hb, row_ptr, esrc, dinv,
                                                scale1, shift1, nullptr, actb, nullptr, N);
    // ---- layer 2
    mm_mfma<<<mm_grid, 256, 0, stream>>>(actb, wt2, dinv, hb, N);
    agg_kernel<0><<<agg_grid, 256, 0, stream>>>(hb, row_ptr, esrc, dinv,
                                                scale2, shift2, nullptr, actb, nullptr, N);
    // ---- layer 3 (+bias +residual, writes fp32 d_out)
    mm_mfma<<<mm_grid, 256, 0, stream>>>(actb, wt3, dinv, hb, N);
    agg_kernel<1><<<agg_grid, 256, 0, stream>>>(hb, row_ptr, esrc, dinv,
                                                b3, nullptr, x, nullptr, out, N);
}